// Round 2
// baseline (124.017 us; speedup 1.0000x reference)
//
#include <hip/hip_runtime.h>
#include <math.h>

// DSA sparse attention, MI355X. B=2 H=8 S=2048 D=64 VD=64 T=128.
// fp32 in/out, int32 indices. One wave per query; 4 waves/block;
// blockIdx%16 = plane=(b*H+h) so blockIdx%8 pins each K/V plane to one XCD L2.
//
// R13: pipeline pass on R12. Counters showed VALUBusy 45%, VGPR=36, HBM 8%,
// L2 gather at ~60-85% of ceiling -> latency/dependency-bound, not BW-bound.
// The compiler scheduled the unrolled loop in a minimal register window
// (36 VGPR!) so only ~1-2 gathers were in flight per wave. Changes:
//  - idx/sc via DIRECT broadcast global loads (ip[tc*8+g]) into arrays at
//    t=0: kills the bpermute serial chain AND the staging dependency; all
//    32 loads are independent and issue immediately. Zero DS ops in kernel.
//  - explicit depth-4 rotating prefetch (kk[4]/vv[4]) for the K/V gather:
//    ~8 L2 loads in flight per wave instead of ~2.
//  - register budget: ~100 VGPR under __launch_bounds__(256,4) (128 cap);
//    occupancy 4 waves/SIMD -- trade waves for per-wave ILP.
// Numerics identical to R12 (same op order): absmax must stay 0.0078125.

#define BB 2
#define HH 8
#define SS 2048
#define DD 64
#define VDD 64
#define TT 128
#define SCALE 0.125f
#define LOG2E 1.44269504088896340736f
#define NKV (BB * HH * SS * DD)          // 2097152 elements each for k and v

typedef __fp16 h2 __attribute__((ext_vector_type(2)));   // builtin interop type
typedef float  f2 __attribute__((ext_vector_type(2)));

__device__ __forceinline__ float bf_lo(unsigned int u) {
    return __uint_as_float(u << 16);
}
// hi bf16 WITHOUT masking: low 16 junk bits are below bf16 rounding noise.
__device__ __forceinline__ float bf_hi(unsigned int u) {
    return __uint_as_float(u);
}
__device__ __forceinline__ unsigned short f2bf_rne(float f) {
    unsigned int u = __float_as_uint(f);
    u += 0x7FFFu + ((u >> 16) & 1u);     // round-to-nearest-even
    return (unsigned short)(u >> 16);
}
__device__ __forceinline__ unsigned int pk_f16(float x, float y) {
    h2 p = __builtin_amdgcn_cvt_pkrtz(x, y);
    return __builtin_bit_cast(unsigned int, p);
}
__device__ __forceinline__ float dot2(unsigned int qh, unsigned int kh, float c) {
    return __builtin_amdgcn_fdot2(__builtin_bit_cast(h2, qh),
                                  __builtin_bit_cast(h2, kh), c, false);
}

// butterfly add via DPP: x += dpp_move(x). All 64 lanes active; row/bank
// masks full, bound_ctrl=1 (no invalid lanes in these patterns).
template <int CTRL>
__device__ __forceinline__ float dpp_add(float x) {
    int t = __builtin_amdgcn_update_dpp(0, __builtin_bit_cast(int, x),
                                        CTRL, 0xF, 0xF, true);
    return x + __builtin_bit_cast(float, t);
}
#define DPP_XOR1 0xB1    // quad_perm(1,0,3,2)
#define DPP_XOR2 0x4E    // quad_perm(2,3,0,1)
#define DPP_OQUAD 0x141  // row_half_mirror: other quad (valid after ^1,^2)
#define DPP_XOR8 0x128   // row_ror:8 == lane^8 within 16-lane row

__device__ __forceinline__ float fast_exp2(float x) {
#if __has_builtin(__builtin_amdgcn_exp2f)
    return __builtin_amdgcn_exp2f(x);
#else
    return exp2f(x);
#endif
}
__device__ __forceinline__ float fast_rcp(float x) {
#if __has_builtin(__builtin_amdgcn_rcpf)
    return __builtin_amdgcn_rcpf(x);
#else
    return 1.0f / x;
#endif
}

// ---- pre-pass: fp32 k -> f16, fp32 v -> bf16, INTERLEAVED per row:
// kv row r (r = plane*SS + s) = [ K: 32 dwords | V: 32 dwords ] = 256 B.
__global__ __launch_bounds__(256) void cvt_kv(
    const float* __restrict__ k, const float* __restrict__ v,
    unsigned int* __restrict__ kv)
{
    int i = (blockIdx.x * 256 + threadIdx.x) * 4;   // 4 floats -> 2 dwords
    if (i >= NKV) return;
    float4 kf = *(const float4*)(k + i);
    float4 vf = *(const float4*)(v + i);
    unsigned int k0 = pk_f16(kf.x, kf.y);
    unsigned int k1 = pk_f16(kf.z, kf.w);
    unsigned int v0 = (unsigned int)f2bf_rne(vf.x) | ((unsigned int)f2bf_rne(vf.y) << 16);
    unsigned int v1 = (unsigned int)f2bf_rne(vf.z) | ((unsigned int)f2bf_rne(vf.w) << 16);
    int r = i >> 6;              // row index (64 fp32 per source row)
    int c = (i & 63) >> 1;       // dword slot within 32-dword half (even)
    unsigned int* row = kv + (size_t)r * 64;
    *(uint2*)(row + c)      = make_uint2(k0, k1);
    *(uint2*)(row + 32 + c) = make_uint2(v0, v1);
}

// ---- main: merged no-max gather loop, barrier-free, LDS-free, DS-free ----
__global__ __launch_bounds__(256, 4) void dsa_sparse_attn_bf16(
    const float* __restrict__ q,
    const unsigned int* __restrict__ kv,   // interleaved rows, 64 dwords each
    const int* __restrict__ topk_idx,
    const float* __restrict__ topk_sc,
    float* __restrict__ out)
{
    const int tid  = threadIdx.x;
    const int wave = tid >> 6;
    const int lane = tid & 63;
    const int h    = lane & 7;           // dim-group: dwords h*4..h*4+3
    const int g    = lane >> 3;          // row-group: rows t = tc*8+g
    const int h16  = h << 4;             // byte offset within row segment

    const int plane = blockIdx.x & 15;
    const int s     = (blockIdx.x >> 4) * 4 + wave;
    const int b     = plane >> 3;

    const float* qp  = q  + ((size_t)plane * SS + s) * DD;
    const char*  kvp = (const char*)(kv + (size_t)plane * (SS * 64));
    const int*   ip  = topk_idx + ((size_t)b * SS + s) * TT;
    const float* scp = topk_sc  + ((size_t)b * SS + s) * TT;
    float*       op  = out + ((size_t)plane * SS + s) * VDD;

    // all idx/sc loads are independent, addresses known at t=0:
    // 8-lane-broadcast loads, issued back-to-back, no DS, no staging chain.
    int idxs[16];
    #pragma unroll
    for (int tc = 0; tc < 16; ++tc) idxs[tc] = ip[tc * 8 + g];
    float scs[16];
    #pragma unroll
    for (int tc = 0; tc < 16; ++tc) scs[tc] = scp[tc * 8 + g];

    float4 qa = *(const float4*)(qp + h * 8);
    float4 qb = *(const float4*)(qp + h * 8 + 4);
    // scale*log2e folded into q -> scores in log2 domain; exp == exp2
    const float QS = SCALE * LOG2E;
    unsigned int q0 = pk_f16(qa.x * QS, qa.y * QS);
    unsigned int q1 = pk_f16(qa.z * QS, qa.w * QS);
    unsigned int q2 = pk_f16(qb.x * QS, qb.y * QS);
    unsigned int q3 = pk_f16(qb.z * QS, qb.w * QS);

    // ---- depth-4 rotating prefetch over the merged no-max loop ----
    uint4 kk[4], vv[4];
    #pragma unroll
    for (int p = 0; p < 4; ++p) {
        const unsigned int off = ((unsigned int)idxs[p] << 8) + h16;
        kk[p] = *(const uint4*)(kvp + off);
        vv[p] = *(const uint4*)(kvp + off + 128);
    }

    f2 a0 = {0.f, 0.f}, a1 = {0.f, 0.f}, a2 = {0.f, 0.f}, a3 = {0.f, 0.f};
    float sum = 0.f;
    #pragma unroll
    for (int tc = 0; tc < 16; ++tc) {
        uint4 kr = kk[tc & 3];
        uint4 vr = vv[tc & 3];
        if (tc < 12) {                    // prefetch iteration tc+4
            const unsigned int off = ((unsigned int)idxs[tc + 4] << 8) + h16;
            kk[tc & 3] = *(const uint4*)(kvp + off);
            vv[tc & 3] = *(const uint4*)(kvp + off + 128);
        }
        float st = dot2(q0, kr.x, dot2(q1, kr.y, dot2(q2, kr.z, dot2(q3, kr.w, 0.f))));
        st = dpp_add<DPP_XOR1>(st);
        st = dpp_add<DPP_XOR2>(st);
        st = dpp_add<DPP_OQUAD>(st);
        float e = fast_exp2(st) * scs[tc];
        sum += e;
        f2 ev = {e, e};
        f2 vx = {bf_lo(vr.x), bf_hi(vr.x)};
        f2 vy = {bf_lo(vr.y), bf_hi(vr.y)};
        f2 vz = {bf_lo(vr.z), bf_hi(vr.z)};
        f2 vw = {bf_lo(vr.w), bf_hi(vr.w)};
        a0 = __builtin_elementwise_fma(ev, vx, a0);
        a1 = __builtin_elementwise_fma(ev, vy, a1);
        a2 = __builtin_elementwise_fma(ev, vz, a2);
        a3 = __builtin_elementwise_fma(ev, vw, a3);
    }

    // cross-lane: weight-sum, then 8 output partials over row-groups (bits 3..5)
    sum = dpp_add<DPP_XOR8>(sum);
    sum += __shfl_xor(sum, 16);
    sum += __shfl_xor(sum, 32);

    float a[8] = {a0.x, a0.y, a1.x, a1.y, a2.x, a2.y, a3.x, a3.y};
    #pragma unroll
    for (int j = 0; j < 8; ++j) {
        a[j] = dpp_add<DPP_XOR8>(a[j]);
        a[j] += __shfl_xor(a[j], 16);
        a[j] += __shfl_xor(a[j], 32);
    }
    if (g == 0) {
        float inv = fast_rcp(sum + 1e-12f);
        *(float4*)(op + h * 8)     = make_float4(a[0] * inv, a[1] * inv, a[2] * inv, a[3] * inv);
        *(float4*)(op + h * 8 + 4) = make_float4(a[4] * inv, a[5] * inv, a[6] * inv, a[7] * inv);
    }
}

// ---- fallback fp32 kernel (used if ws too small) ----
__global__ __launch_bounds__(256, 4) void dsa_sparse_attn_f32(
    const float* __restrict__ q,
    const float* __restrict__ k,
    const float* __restrict__ v,
    const int* __restrict__ topk_idx,
    const float* __restrict__ topk_sc,
    float* __restrict__ out)
{
    const int tid  = threadIdx.x;
    const int wave = tid >> 6;
    const int lane = tid & 63;
    const int plane = blockIdx.x & 15;
    const int s     = (blockIdx.x >> 4) * 4 + wave;
    const int b     = plane >> 3;

    const float* qp  = q + ((size_t)plane * SS + s) * DD;
    const float* kp  = k + (size_t)plane * SS * DD;
    const float* vp  = v + (size_t)plane * SS * VDD;
    const int*   ip  = topk_idx + ((size_t)b * SS + s) * TT;
    const float* scp = topk_sc  + ((size_t)b * SS + s) * TT;
    float*       op  = out + ((size_t)plane * SS + s) * VDD;

    __shared__ int   s_idx[4][TT];
    __shared__ float s_w[4][TT];

    float sc0 = scp[lane];
    float sc1 = scp[64 + lane];
    s_idx[wave][lane]      = ip[lane];
    s_idx[wave][64 + lane] = ip[64 + lane];

    const int l = lane & 3;
    const int g = lane >> 2;
    float4 qf[4];
    #pragma unroll
    for (int j = 0; j < 4; ++j) qf[j] = *(const float4*)(qp + l * 4 + 16 * j);
    __syncthreads();

    #pragma unroll
    for (int tc = 0; tc < 8; ++tc) {
        int t = tc * 16 + g;
        const float* krow = kp + (size_t)s_idx[wave][t] * DD;
        float acc = 0.f;
        #pragma unroll
        for (int j = 0; j < 4; ++j) {
            float4 kf = *(const float4*)(krow + l * 4 + 16 * j);
            acc += qf[j].x * kf.x + qf[j].y * kf.y + qf[j].z * kf.z + qf[j].w * kf.w;
        }
        acc += __shfl_xor(acc, 1);
        acc += __shfl_xor(acc, 2);
        if (l == 0) s_w[wave][t] = acc * SCALE;
    }
    __syncthreads();

    float a0 = s_w[wave][lane];
    float a1 = s_w[wave][64 + lane];
    float m = fmaxf(a0, a1);
    #pragma unroll
    for (int off = 32; off >= 1; off >>= 1) m = fmaxf(m, __shfl_xor(m, off));
    float e0 = __expf(a0 - m) * sc0;
    float e1 = __expf(a1 - m) * sc1;
    float sum = e0 + e1;
    #pragma unroll
    for (int off = 32; off >= 1; off >>= 1) sum += __shfl_xor(sum, off);
    float inv = 1.0f / (sum + 1e-12f);
    s_w[wave][lane]      = e0 * inv;
    s_w[wave][64 + lane] = e1 * inv;
    __syncthreads();

    float acc = 0.f;
    #pragma unroll 8
    for (int t = 0; t < TT; ++t)
        acc = fmaf(s_w[wave][t], vp[(size_t)s_idx[wave][t] * VDD + lane], acc);
    op[lane] = acc;
}

extern "C" void kernel_launch(void* const* d_in, const int* in_sizes, int n_in,
                              void* d_out, int out_size, void* d_ws, size_t ws_size,
                              hipStream_t stream) {
    const float* q   = (const float*)d_in[0];
    const float* k   = (const float*)d_in[1];
    const float* v   = (const float*)d_in[2];
    const int*   idx = (const int*)d_in[3];
    const float* sc  = (const float*)d_in[4];
    float*       out = (float*)d_out;

    const size_t need = (size_t)NKV * 2 * 2;   // interleaved kv, 8.4 MB
    if (ws_size >= need) {
        unsigned int* kv = (unsigned int*)d_ws;
        hipLaunchKernelGGL(cvt_kv, dim3(NKV / 4 / 256), dim3(256), 0, stream,
                           k, v, kv);
        hipLaunchKernelGGL(dsa_sparse_attn_bf16, dim3(8192), dim3(256), 0, stream,
                           q, kv, idx, sc, out);
    } else {
        hipLaunchKernelGGL(dsa_sparse_attn_f32, dim3(8192), dim3(256), 0, stream,
                           q, k, v, idx, sc, out);
    }
}

// Round 3
// 121.939 us; speedup vs baseline: 1.0170x; 1.0170x over previous
//
#include <hip/hip_runtime.h>
#include <math.h>

// DSA sparse attention, MI355X. B=2 H=8 S=2048 D=64 VD=64 T=128.
// fp32 in/out, int32 indices. One wave per query; 4 waves/block;
// blockIdx%16 = plane=(b*H+h) so blockIdx%8 pins each K/V plane to one XCD L2.
//
// R14: hand-scheduled gather pipeline. R13 post-mortem: compiler re-sank the
// rotating-buffer prefetch (VGPR stayed 40!) -> still ~2 loads in flight,
// latency-bound at ~250cy/iter. Model: 16 iter x (250cy L2 gather + 50cy
// compute) x 32 waves/SIMD = 51us == measured. Fix: take the pipeline away
// from the compiler (T4 / AITER pattern):
//  - inline-asm global_load_dwordx4 (saddr form) for K/V, 4 pair-buffers,
//    8 loads permanently in flight, counted s_waitcnt vmcnt(6) per iter
//    (never 0 mid-loop), sched_barrier(0) after each wait (rule #18).
//  - all compiler VMEM (idx->voff, sc, q) forced complete BEFORE the loop
//    (keep-alive asm), so no compiler waitcnts inside the loop.
//  - fully unrolled; voffs/scs arrays live in VGPRs (~90 VGPR, 4 waves/SIMD:
//    trade occupancy for 4x in-flight gathers).
// Numerics identical to R12/R13: absmax must stay 0.0078125.

#define BB 2
#define HH 8
#define SS 2048
#define DD 64
#define VDD 64
#define TT 128
#define SCALE 0.125f
#define LOG2E 1.44269504088896340736f
#define NKV (BB * HH * SS * DD)          // 2097152 elements each for k and v

typedef __fp16 h2 __attribute__((ext_vector_type(2)));   // builtin interop type
typedef float  f2 __attribute__((ext_vector_type(2)));

__device__ __forceinline__ float bf_lo(unsigned int u) {
    return __uint_as_float(u << 16);
}
// hi bf16 WITHOUT masking: low 16 junk bits are below bf16 rounding noise.
__device__ __forceinline__ float bf_hi(unsigned int u) {
    return __uint_as_float(u);
}
__device__ __forceinline__ unsigned short f2bf_rne(float f) {
    unsigned int u = __float_as_uint(f);
    u += 0x7FFFu + ((u >> 16) & 1u);     // round-to-nearest-even
    return (unsigned short)(u >> 16);
}
__device__ __forceinline__ unsigned int pk_f16(float x, float y) {
    h2 p = __builtin_amdgcn_cvt_pkrtz(x, y);
    return __builtin_bit_cast(unsigned int, p);
}
__device__ __forceinline__ float dot2(unsigned int qh, unsigned int kh, float c) {
    return __builtin_amdgcn_fdot2(__builtin_bit_cast(h2, qh),
                                  __builtin_bit_cast(h2, kh), c, false);
}

// butterfly add via DPP: x += dpp_move(x). All 64 lanes active; row/bank
// masks full, bound_ctrl=1 (no invalid lanes in these patterns).
template <int CTRL>
__device__ __forceinline__ float dpp_add(float x) {
    int t = __builtin_amdgcn_update_dpp(0, __builtin_bit_cast(int, x),
                                        CTRL, 0xF, 0xF, true);
    return x + __builtin_bit_cast(float, t);
}
#define DPP_XOR1 0xB1    // quad_perm(1,0,3,2)
#define DPP_XOR2 0x4E    // quad_perm(2,3,0,1)
#define DPP_OQUAD 0x141  // row_half_mirror: other quad (valid after ^1,^2)
#define DPP_XOR8 0x128   // row_ror:8 == lane^8 within 16-lane row

__device__ __forceinline__ float fast_exp2(float x) {
#if __has_builtin(__builtin_amdgcn_exp2f)
    return __builtin_amdgcn_exp2f(x);
#else
    return exp2f(x);
#endif
}
__device__ __forceinline__ float fast_rcp(float x) {
#if __has_builtin(__builtin_amdgcn_rcpf)
    return __builtin_amdgcn_rcpf(x);
#else
    return 1.0f / x;
#endif
}

// ---- pre-pass: fp32 k -> f16, fp32 v -> bf16, INTERLEAVED per row:
// kv row r (r = plane*SS + s) = [ K: 32 dwords | V: 32 dwords ] = 256 B.
__global__ __launch_bounds__(256) void cvt_kv(
    const float* __restrict__ k, const float* __restrict__ v,
    unsigned int* __restrict__ kv)
{
    int i = (blockIdx.x * 256 + threadIdx.x) * 4;   // 4 floats -> 2 dwords
    if (i >= NKV) return;
    float4 kf = *(const float4*)(k + i);
    float4 vf = *(const float4*)(v + i);
    unsigned int k0 = pk_f16(kf.x, kf.y);
    unsigned int k1 = pk_f16(kf.z, kf.w);
    unsigned int v0 = (unsigned int)f2bf_rne(vf.x) | ((unsigned int)f2bf_rne(vf.y) << 16);
    unsigned int v1 = (unsigned int)f2bf_rne(vf.z) | ((unsigned int)f2bf_rne(vf.w) << 16);
    int r = i >> 6;              // row index (64 fp32 per source row)
    int c = (i & 63) >> 1;       // dword slot within 32-dword half (even)
    unsigned int* row = kv + (size_t)r * 64;
    *(uint2*)(row + c)      = make_uint2(k0, k1);
    *(uint2*)(row + 32 + c) = make_uint2(v0, v1);
}

// asm gather: dst <- kv[base(SGPR) + voff(VGPR) + IMM]
#define GLD(dst, vo, IMM) \
    asm volatile("global_load_dwordx4 %0, %1, %2 offset:" #IMM \
                 : "=v"(dst) : "v"(vo), "s"(kvp))

#define WAITV(N) \
    asm volatile("s_waitcnt vmcnt(" #N ")" ::: "memory"); \
    __builtin_amdgcn_sched_barrier(0)

// one pipeline stage: wait for this pair, score+accumulate
#define BODY(TC, KB, VB) \
    { \
        float st = dot2(q0, KB.x, dot2(q1, KB.y, dot2(q2, KB.z, dot2(q3, KB.w, 0.f)))); \
        st = dpp_add<DPP_XOR1>(st); \
        st = dpp_add<DPP_XOR2>(st); \
        st = dpp_add<DPP_OQUAD>(st); \
        float e = fast_exp2(st) * scs[TC]; \
        sum += e; \
        f2 ev = {e, e}; \
        f2 vx = {bf_lo(VB.x), bf_hi(VB.x)}; \
        f2 vy = {bf_lo(VB.y), bf_hi(VB.y)}; \
        f2 vz = {bf_lo(VB.z), bf_hi(VB.z)}; \
        f2 vw = {bf_lo(VB.w), bf_hi(VB.w)}; \
        a0 = __builtin_elementwise_fma(ev, vx, a0); \
        a1 = __builtin_elementwise_fma(ev, vy, a1); \
        a2 = __builtin_elementwise_fma(ev, vz, a2); \
        a3 = __builtin_elementwise_fma(ev, vw, a3); \
    }

#define ITERP(TC, KB, VB) \
    WAITV(6); \
    BODY(TC, KB, VB); \
    GLD(KB, voffs[(TC) + 4], 0); \
    GLD(VB, voffs[(TC) + 4], 128)

// ---- main: merged no-max gather loop; hand-counted vmcnt pipeline ----
__global__ __launch_bounds__(256, 4) void dsa_sparse_attn_bf16(
    const float* __restrict__ q,
    const unsigned int* __restrict__ kv,   // interleaved rows, 64 dwords each
    const int* __restrict__ topk_idx,
    const float* __restrict__ topk_sc,
    float* __restrict__ out)
{
    const int tid  = threadIdx.x;
    const int wave = tid >> 6;
    const int lane = tid & 63;
    const int h    = lane & 7;           // dim-group: dwords h*4..h*4+3
    const int g    = lane >> 3;          // row-group: rows t = tc*8+g
    const int h16  = h << 4;             // byte offset within row segment

    const int plane = blockIdx.x & 15;
    const int s     = (blockIdx.x >> 4) * 4 + wave;
    const int b     = plane >> 3;

    const float* qp  = q  + ((size_t)plane * SS + s) * DD;
    const char*  kvp = (const char*)(kv + (size_t)plane * (SS * 64));
    const int*   ip  = topk_idx + ((size_t)b * SS + s) * TT;
    const float* scp = topk_sc  + ((size_t)b * SS + s) * TT;
    float*       op  = out + ((size_t)plane * SS + s) * VDD;

    // all idx/sc loads independent, addresses known at t=0 (8-lane broadcast).
    // voff computation forces idx loads complete before the loop.
    int voffs[16];
    #pragma unroll
    for (int tc = 0; tc < 16; ++tc)
        voffs[tc] = (ip[tc * 8 + g] << 8) + h16;
    float scs[16];
    #pragma unroll
    for (int tc = 0; tc < 16; ++tc) scs[tc] = scp[tc * 8 + g];

    float4 qa = *(const float4*)(qp + h * 8);
    float4 qb = *(const float4*)(qp + h * 8 + 4);
    // scale*log2e folded into q -> scores in log2 domain; exp == exp2
    const float QS = SCALE * LOG2E;
    unsigned int q0 = pk_f16(qa.x * QS, qa.y * QS);
    unsigned int q1 = pk_f16(qa.z * QS, qa.w * QS);
    unsigned int q2 = pk_f16(qb.x * QS, qb.y * QS);
    unsigned int q3 = pk_f16(qb.z * QS, qb.w * QS);

    // force every loop-consumed value into a register NOW: after this fence
    // the compiler has no outstanding VMEM, so the loop contains only our
    // asm loads and our counted waits.
    #pragma unroll
    for (int tc = 0; tc < 16; ++tc)
        asm volatile("" :: "v"(voffs[tc]), "v"(scs[tc]));
    asm volatile("" :: "v"(q0), "v"(q1), "v"(q2), "v"(q3));
    __builtin_amdgcn_sched_barrier(0);

    f2 a0 = {0.f, 0.f}, a1 = {0.f, 0.f}, a2 = {0.f, 0.f}, a3 = {0.f, 0.f};
    float sum = 0.f;

    uint4 KB0, VB0, KB1, VB1, KB2, VB2, KB3, VB3;
    // prologue: fill the 4-deep pipeline (8 loads in flight)
    GLD(KB0, voffs[0], 0); GLD(VB0, voffs[0], 128);
    GLD(KB1, voffs[1], 0); GLD(VB1, voffs[1], 128);
    GLD(KB2, voffs[2], 0); GLD(VB2, voffs[2], 128);
    GLD(KB3, voffs[3], 0); GLD(VB3, voffs[3], 128);

    ITERP( 0, KB0, VB0);
    ITERP( 1, KB1, VB1);
    ITERP( 2, KB2, VB2);
    ITERP( 3, KB3, VB3);
    ITERP( 4, KB0, VB0);
    ITERP( 5, KB1, VB1);
    ITERP( 6, KB2, VB2);
    ITERP( 7, KB3, VB3);
    ITERP( 8, KB0, VB0);
    ITERP( 9, KB1, VB1);
    ITERP(10, KB2, VB2);
    ITERP(11, KB3, VB3);
    // drain: no more issues; counted waits step down
    WAITV(6);  BODY(12, KB0, VB0);
    WAITV(4);  BODY(13, KB1, VB1);
    WAITV(2);  BODY(14, KB2, VB2);
    WAITV(0);  BODY(15, KB3, VB3);

    // cross-lane: weight-sum, then 8 output partials over row-groups (bits 3..5)
    sum = dpp_add<DPP_XOR8>(sum);
    sum += __shfl_xor(sum, 16);
    sum += __shfl_xor(sum, 32);

    float a[8] = {a0.x, a0.y, a1.x, a1.y, a2.x, a2.y, a3.x, a3.y};
    #pragma unroll
    for (int j = 0; j < 8; ++j) {
        a[j] = dpp_add<DPP_XOR8>(a[j]);
        a[j] += __shfl_xor(a[j], 16);
        a[j] += __shfl_xor(a[j], 32);
    }
    if (g == 0) {
        float inv = fast_rcp(sum + 1e-12f);
        *(float4*)(op + h * 8)     = make_float4(a[0] * inv, a[1] * inv, a[2] * inv, a[3] * inv);
        *(float4*)(op + h * 8 + 4) = make_float4(a[4] * inv, a[5] * inv, a[6] * inv, a[7] * inv);
    }
}

// ---- fallback fp32 kernel (used if ws too small) ----
__global__ __launch_bounds__(256, 4) void dsa_sparse_attn_f32(
    const float* __restrict__ q,
    const float* __restrict__ k,
    const float* __restrict__ v,
    const int* __restrict__ topk_idx,
    const float* __restrict__ topk_sc,
    float* __restrict__ out)
{
    const int tid  = threadIdx.x;
    const int wave = tid >> 6;
    const int lane = tid & 63;
    const int plane = blockIdx.x & 15;
    const int s     = (blockIdx.x >> 4) * 4 + wave;
    const int b     = plane >> 3;

    const float* qp  = q + ((size_t)plane * SS + s) * DD;
    const float* kp  = k + (size_t)plane * SS * DD;
    const float* vp  = v + (size_t)plane * SS * VDD;
    const int*   ip  = topk_idx + ((size_t)b * SS + s) * TT;
    const float* scp = topk_sc  + ((size_t)b * SS + s) * TT;
    float*       op  = out + ((size_t)plane * SS + s) * VDD;

    __shared__ int   s_idx[4][TT];
    __shared__ float s_w[4][TT];

    float sc0 = scp[lane];
    float sc1 = scp[64 + lane];
    s_idx[wave][lane]      = ip[lane];
    s_idx[wave][64 + lane] = ip[64 + lane];

    const int l = lane & 3;
    const int g = lane >> 2;
    float4 qf[4];
    #pragma unroll
    for (int j = 0; j < 4; ++j) qf[j] = *(const float4*)(qp + l * 4 + 16 * j);
    __syncthreads();

    #pragma unroll
    for (int tc = 0; tc < 8; ++tc) {
        int t = tc * 16 + g;
        const float* krow = kp + (size_t)s_idx[wave][t] * DD;
        float acc = 0.f;
        #pragma unroll
        for (int j = 0; j < 4; ++j) {
            float4 kf = *(const float4*)(krow + l * 4 + 16 * j);
            acc += qf[j].x * kf.x + qf[j].y * kf.y + qf[j].z * kf.z + qf[j].w * kf.w;
        }
        acc += __shfl_xor(acc, 1);
        acc += __shfl_xor(acc, 2);
        if (l == 0) s_w[wave][t] = acc * SCALE;
    }
    __syncthreads();

    float a0 = s_w[wave][lane];
    float a1 = s_w[wave][64 + lane];
    float m = fmaxf(a0, a1);
    #pragma unroll
    for (int off = 32; off >= 1; off >>= 1) m = fmaxf(m, __shfl_xor(m, off));
    float e0 = __expf(a0 - m) * sc0;
    float e1 = __expf(a1 - m) * sc1;
    float sum = e0 + e1;
    #pragma unroll
    for (int off = 32; off >= 1; off >>= 1) sum += __shfl_xor(sum, off);
    float inv = 1.0f / (sum + 1e-12f);
    s_w[wave][lane]      = e0 * inv;
    s_w[wave][64 + lane] = e1 * inv;
    __syncthreads();

    float acc = 0.f;
    #pragma unroll 8
    for (int t = 0; t < TT; ++t)
        acc = fmaf(s_w[wave][t], vp[(size_t)s_idx[wave][t] * VDD + lane], acc);
    op[lane] = acc;
}

extern "C" void kernel_launch(void* const* d_in, const int* in_sizes, int n_in,
                              void* d_out, int out_size, void* d_ws, size_t ws_size,
                              hipStream_t stream) {
    const float* q   = (const float*)d_in[0];
    const float* k   = (const float*)d_in[1];
    const float* v   = (const float*)d_in[2];
    const int*   idx = (const int*)d_in[3];
    const float* sc  = (const float*)d_in[4];
    float*       out = (float*)d_out;

    const size_t need = (size_t)NKV * 2 * 2;   // interleaved kv, 8.4 MB
    if (ws_size >= need) {
        unsigned int* kv = (unsigned int*)d_ws;
        hipLaunchKernelGGL(cvt_kv, dim3(NKV / 4 / 256), dim3(256), 0, stream,
                           k, v, kv);
        hipLaunchKernelGGL(dsa_sparse_attn_bf16, dim3(8192), dim3(256), 0, stream,
                           q, kv, idx, sc, out);
    } else {
        hipLaunchKernelGGL(dsa_sparse_attn_f32, dim3(8192), dim3(256), 0, stream,
                           q, k, v, idx, sc, out);
    }
}